// Round 1
// baseline (122.979 us; speedup 1.0000x reference)
//
#include <hip/hip_runtime.h>
#include <hip/hip_bf16.h>
#include <math.h>

#define NA 250000
#define NG 64
#define NP 4096

#define SPAN 512                        // anchors per scan block
#define NB ((NA + SPAN - 1) / SPAN)     // 489 scan blocks
#define NBP 512                         // padded best-table width
#define RBLK (NP / 256)                 // 16 ROI blocks (appended to kA)

// ws float layout
#define OFF_TAB    0                             // [NG][NBP] per-(g,block) max
#define OFF_MAXARG (OFF_TAB + NG * NBP)          // float2 per anchor: (max, arg bits)
#define OFF_ROI    (OFF_MAXARG + 2 * NB * SPAN)  // 16 x 2
#define OFF_SUM    (OFF_ROI + RBLK * 2)          // NB x 4
#define OFF_CNT    (OFF_SUM + NB * 4)            // int completion counter

// ---------- shared math helpers ----------

// IoU and areas must be bitwise identical between kA (scan) and kB (force
// re-scan): contraction pinned off; identical inlined op sequences.
static __device__ __forceinline__ float area_of(float4 b) {
#pragma clang fp contract(off)
    return (b.z - b.x) * (b.w - b.y);
}

static __device__ __forceinline__ float iou_one(
    float gx0, float gy0, float gx1, float gy1, float ga,
    float ax0, float ay0, float ax1, float ay1, float aa)
{
#pragma clang fp contract(off)
    float ltx = fmaxf(gx0, ax0);
    float lty = fmaxf(gy0, ay0);
    float rbx = fminf(gx1, ax1);
    float rby = fminf(gy1, ay1);
    float w = fmaxf(rbx - ltx, 0.0f);
    float h = fmaxf(rby - lty, 0.0f);
    float inter = w * h;
    float uni = ga + aa - inter;
    return inter * __builtin_amdgcn_rcpf(uni);   // uni > 0 always
}

static __device__ __forceinline__ float smooth_l1_f(float d) {
    const float BETA = 1.0f / 9.0f;
    float ad = fabsf(d);
    return (ad < BETA) ? (0.5f * d * d / BETA) : (ad - 0.5f * BETA);
}

// ---------- kernel A: unified anchor-major scan (+ROI blocks) ----------
// blocks [0,NB): per-anchor max/argmax -> maxarg; per-(g,block) max -> table.
// blocks [NB,NB+RBLK): ROI losses -> OFF_ROI; zero table pad columns;
//                      block NB (r==0) re-inits the completion counter.

__global__ __launch_bounds__(256) void kA(const float4* __restrict__ anchors,
                                          const float4* __restrict__ gt,
                                          const float* __restrict__ logits,
                                          const float* __restrict__ breg,
                                          const int* __restrict__ rlab,
                                          const float4* __restrict__ rtgt,
                                          const float* __restrict__ rsc,
                                          float* __restrict__ ws) {
    int t = threadIdx.x;
    int b = blockIdx.x;

    if (b >= NB) {
        // ---- ROI block ----
        int r = b - NB;
        if (r == 0 && t == 0) *(int*)(ws + OFF_CNT) = 0;   // re-init each launch
        // zero table pad columns for rows [4r, 4r+4)
        if (t < NBP - NB) {
#pragma unroll
            for (int row = 0; row < 4; row++)
                ws[OFF_TAB + (4 * r + row) * NBP + NB + t] = 0.0f;
        }
        __shared__ float rbuf[4][2];
        int p = r * 256 + t;                 // 16*256 == NP
        float l0 = logits[2 * p], l1 = logits[2 * p + 1];
        float mx = fmaxf(l0, l1);
        float lse = mx + __logf(__expf(l0 - mx) + __expf(l1 - mx));
        float s = rsc[p];
        float clsl = -((1.0f - s) * (l0 - lse) + s * (l1 - lse));

        int lbl = rlab[p];
        int cl = lbl < 0 ? 0 : lbl;
        float4 bb = *(const float4*)(breg + 8 * p + 4 * cl);
        float4 tg = rtgt[p];
        float sl = smooth_l1_f(bb.x - tg.x) + smooth_l1_f(bb.y - tg.y) +
                   smooth_l1_f(bb.z - tg.z) + smooth_l1_f(bb.w - tg.w);
        float boxl = (lbl > 0) ? sl : 0.0f;

        int lane = t & 63, w = t >> 6;
        for (int off = 32; off > 0; off >>= 1) {
            clsl += __shfl_down(clsl, off);
            boxl += __shfl_down(boxl, off);
        }
        if (lane == 0) { rbuf[w][0] = clsl; rbuf[w][1] = boxl; }
        __syncthreads();
        if (t == 0) {
            float s0 = 0.f, s1 = 0.f;
            for (int i = 0; i < 4; i++) { s0 += rbuf[i][0]; s1 += rbuf[i][1]; }
            ws[OFF_ROI + 2 * r] = s0;
            ws[OFF_ROI + 2 * r + 1] = s1;
        }
        return;
    }

    // ---- scan block ----
    int a0 = b * SPAN + t;
    int a1 = a0 + 256;
    bool ok0 = a0 < NA, ok1 = a1 < NA;
    float4 av0 = ok0 ? anchors[a0] : make_float4(0.f, 0.f, 0.f, 0.f);
    float4 av1 = ok1 ? anchors[a1] : make_float4(0.f, 0.f, 0.f, 0.f);
    float aa0 = area_of(av0);
    float aa1 = area_of(av1);

    float m[NG];
#pragma unroll
    for (int g = 0; g < NG; g++) m[g] = 0.0f;

    float max0 = -1.0f, max1 = -1.0f;
    int arg0 = 0, arg1 = 0;
#pragma unroll
    for (int g = 0; g < NG; g++) {
        float4 G = gt[g];                    // uniform -> s_load
        float ga = area_of(G);
        float u0 = iou_one(G.x, G.y, G.z, G.w, ga, av0.x, av0.y, av0.z, av0.w, aa0);
        float u1 = iou_one(G.x, G.y, G.z, G.w, ga, av1.x, av1.y, av1.z, av1.w, aa1);
        if (u0 > max0) { max0 = u0; arg0 = g; }   // first-max == jnp.argmax
        if (u1 > max1) { max1 = u1; arg1 = g; }
        m[g] = fmaxf(m[g], fmaxf(u0, u1));        // fake anchors give 0: harmless
    }

    float2* ma = (float2*)(ws + OFF_MAXARG);
    if (ok0) ma[a0] = make_float2(max0, __int_as_float(arg0));
    if (ok1) ma[a1] = make_float2(max1, __int_as_float(arg1));

    // per-(g,block) reduce: 6 shuffles per g, then 4-wave LDS combine
    __shared__ float sred[4][NG];
    int lane = t & 63, w = t >> 6;
#pragma unroll
    for (int g = 0; g < NG; g++) {
        float mm = m[g];
        for (int off = 32; off > 0; off >>= 1)
            mm = fmaxf(mm, __shfl_down(mm, off));
        if (lane == 0) sred[w][g] = mm;
    }
    __syncthreads();
    if (t < NG) {
        float mm = fmaxf(fmaxf(sred[0][t], sred[1][t]),
                         fmaxf(sred[2][t], sred[3][t]));
        ws[OFF_TAB + t * NBP + b] = mm;      // plain store
    }
}

// ---------- kernel B: best-per-gt + in-register force + epilogue ----------
// Each block: (1) reduce the full 64x512 table (128 KB, L2-hot) to best[g];
// (2) candidate gts = {g : tab[g][b] == best[g]}; re-scan ONLY this block's
// anchors against candidates (bitwise-identical iou) -> force in registers;
// (3) per-anchor labels + losses; (4) partial sums; last block finishes
// the final double-precision reduction (old kernel C).

__global__ __launch_bounds__(256) void kB(const float4* __restrict__ anchors,
                                          const float* __restrict__ objness,
                                          const float4* __restrict__ pdel,
                                          const float4* __restrict__ gt,
                                          const float* __restrict__ gscore,
                                          const int* __restrict__ gconf,
                                          float* __restrict__ ws,
                                          float* __restrict__ out) {
    __shared__ float sbest[NG];
    __shared__ int   scand[NG];
    __shared__ int   scnt;
    __shared__ float rbuf[4][4];
    __shared__ bool  islast;

    int t = threadIdx.x;
    int b = blockIdx.x;
    int lane = t & 63, w = t >> 6;

    if (t == 0) scnt = 0;

    // ---- (1) global best per gt from the table ----
    {
        int g = t >> 2, quad = t & 3;
        const float4* rowv = (const float4*)(ws + OFF_TAB + g * NBP + quad * 128);
        float mm = 0.0f;                      // iou >= 0 always
#pragma unroll
        for (int j = 0; j < 32; j++) {
            float4 v = rowv[j];
            mm = fmaxf(mm, fmaxf(fmaxf(v.x, v.y), fmaxf(v.z, v.w)));
        }
        mm = fmaxf(mm, __shfl_xor(mm, 1));    // combine the 4 lanes of this g
        mm = fmaxf(mm, __shfl_xor(mm, 2));
        if (quad == 0) sbest[g] = mm;
    }
    __syncthreads();

    // ---- (2) candidate gts for this block ----
    if (t < NG) {
        if (ws[OFF_TAB + t * NBP + b] == sbest[t]) {
            int i = atomicAdd(&scnt, 1);
            scand[i] = t;
        }
    }
    __syncthreads();
    int cnt = scnt;

    const float2* ma = (const float2*)(ws + OFF_MAXARG);

    float posf = 0.f, negf = 0.f, slpos = 0.f, bces = 0.f;
#pragma unroll
    for (int k = 0; k < 2; k++) {
        int a = b * SPAN + k * 256 + t;
        if (a >= NA) continue;
        float2 mv = ma[a];
        float maxv = mv.x;
        int arg = __float_as_int(mv.y);

        float4 av = anchors[a];
        float aa = area_of(av);

        // in-register force detection (replaces old kernel F)
        bool force = false;
        for (int i = 0; i < cnt; i++) {
            int g = scand[i];
            float4 G = gt[g];                // uniform -> s_load
            float ga = area_of(G);
            float u = iou_one(G.x, G.y, G.z, G.w, ga, av.x, av.y, av.z, av.w, aa);
            force |= (u == sbest[g]);
        }

        int matched = (maxv < 0.3f) ? -1 : ((maxv < 0.7f) ? -2 : arg);
        if (force) matched = arg;
        int cl = matched < 0 ? 0 : matched;

        float4 Ac = gt[cl];                  // per-lane gather, 1KB L1-hot
        float score = gscore[cl];
        int conf = gconf[cl];
        float label = (matched >= 0) ? 1.0f : 0.0f;
        label = fminf(label, score);
        if (matched == -1) label = 0.0f;
        if (matched == -2) label = -1.0f;
        if (conf == 0 && matched >= 0) label = -1.0f;

        bool pos = (label >= 1.0f);
        bool neg = (label == 0.0f);
        bool sel = pos || neg;

        float aw = av.z - av.x, ah = av.w - av.y;
        float acx = av.x + 0.5f * aw, acy = av.y + 0.5f * ah;
        float gw = Ac.z - Ac.x, gh = Ac.w - Ac.y;
        float gcx = Ac.x + 0.5f * gw, gcy = Ac.y + 0.5f * gh;
        float t0 = (gcx - acx) / aw;
        float t1 = (gcy - acy) / ah;
        float t2 = __logf(gw / aw);
        float t3 = __logf(gh / ah);

        float4 pd = pdel[a];
        float sl = smooth_l1_f(pd.x - t0) + smooth_l1_f(pd.y - t1) +
                   smooth_l1_f(pd.z - t2) + smooth_l1_f(pd.w - t3);

        float x = objness[a];
        float y = sel ? fminf(fmaxf(label, 0.0f), 1.0f) : 0.0f;
        float bce = fmaxf(x, 0.0f) - x * y + __logf(1.0f + __expf(-fabsf(x)));

        if (pos) { posf += 1.0f; slpos += sl; }
        if (neg) negf += 1.0f;
        if (sel) bces += bce;
    }

    for (int off = 32; off > 0; off >>= 1) {
        posf  += __shfl_down(posf, off);
        negf  += __shfl_down(negf, off);
        slpos += __shfl_down(slpos, off);
        bces  += __shfl_down(bces, off);
    }
    if (lane == 0) { rbuf[w][0] = posf; rbuf[w][1] = negf; rbuf[w][2] = slpos; rbuf[w][3] = bces; }
    __syncthreads();
    if (t == 0) {
        float s0 = 0.f, s1 = 0.f, s2 = 0.f, s3 = 0.f;
        for (int i = 0; i < 4; i++) { s0 += rbuf[i][0]; s1 += rbuf[i][1]; s2 += rbuf[i][2]; s3 += rbuf[i][3]; }
        float* r = ws + OFF_SUM + 4 * b;
        r[0] = s0; r[1] = s1; r[2] = s2; r[3] = s3;
        __threadfence();                                   // release partials
        int prev = atomicAdd((int*)(ws + OFF_CNT), 1);     // device-scope
        islast = (prev == NB - 1);
    }
    __syncthreads();
    if (!islast) return;
    __threadfence();                                       // acquire partials

    // ---- (4) final reduce (old kernel C), last block only ----
    __shared__ double sredc[4][6];
    double a0 = 0, a1 = 0, a2 = 0, a3 = 0, c0 = 0, c1 = 0;
    for (int r = t; r < NB; r += 256) {
        const float4 v = *(const float4*)(ws + OFF_SUM + 4 * r);
        a0 += v.x; a1 += v.y; a2 += v.z; a3 += v.w;
    }
    if (t < RBLK) {
        c0 = ws[OFF_ROI + 2 * t];
        c1 = ws[OFF_ROI + 2 * t + 1];
    }
    for (int off = 32; off > 0; off >>= 1) {
        a0 += __shfl_down(a0, off);
        a1 += __shfl_down(a1, off);
        a2 += __shfl_down(a2, off);
        a3 += __shfl_down(a3, off);
        c0 += __shfl_down(c0, off);
        c1 += __shfl_down(c1, off);
    }
    if (lane == 0) {
        sredc[w][0] = a0; sredc[w][1] = a1; sredc[w][2] = a2;
        sredc[w][3] = a3; sredc[w][4] = c0; sredc[w][5] = c1;
    }
    __syncthreads();
    if (t == 0) {
        double s[6] = {0, 0, 0, 0, 0, 0};
        for (int i = 0; i < 4; i++)
            for (int j = 0; j < 6; j++) s[j] += sredc[i][j];
        double n = s[0] + s[1];
        out[0] = (float)(s[3] / n);            // objectness_loss
        out[1] = (float)(s[2] / n);            // rpn_box_loss
        out[2] = (float)(s[4] / (double)NP);   // classification_loss
        out[3] = (float)(s[5] / (double)NP);   // roi_box_loss
    }
}

extern "C" void kernel_launch(void* const* d_in, const int* in_sizes, int n_in,
                              void* d_out, int out_size, void* d_ws, size_t ws_size,
                              hipStream_t stream) {
    const float4* anchors = (const float4*)d_in[0];
    const float4* gt      = (const float4*)d_in[1];
    const float*  gscore  = (const float*)d_in[2];
    const int*    gconf   = (const int*)d_in[3];
    const float*  objness = (const float*)d_in[4];
    const float4* pdel    = (const float4*)d_in[5];
    const float*  clog    = (const float*)d_in[6];
    const float*  breg    = (const float*)d_in[7];
    const int*    rlab    = (const int*)d_in[8];
    const float4* rtgt    = (const float4*)d_in[9];
    const float*  rsc     = (const float*)d_in[10];

    float* ws = (float*)d_ws;
    float* out = (float*)d_out;

    kA<<<NB + RBLK, 256, 0, stream>>>(anchors, gt, clog, breg, rlab, rtgt, rsc, ws);
    kB<<<NB, 256, 0, stream>>>(anchors, objness, pdel, gt, gscore, gconf, ws, out);
}

// Round 2
// 117.268 us; speedup vs baseline: 1.0487x; 1.0487x over previous
//
#include <hip/hip_runtime.h>
#include <hip/hip_bf16.h>
#include <math.h>

#define NA 250000
#define NG 64
#define NP 4096

#define SPAN 512                        // anchors per scan block
#define NB ((NA + SPAN - 1) / SPAN)     // 489 scan blocks
#define NBP 512                         // padded best-table width
#define RBLK (NP / 256)                 // 16 ROI blocks (appended to kA)

// ws float layout
#define OFF_TAB    0                             // [NG][NBP] per-(g,block) max
#define OFF_MAXARG (OFF_TAB + NG * NBP)          // float2 per anchor: (max, arg bits)
#define OFF_ROI    (OFF_MAXARG + 2 * NB * SPAN)  // 16 x 2
#define OFF_SUM    (OFF_ROI + RBLK * 2)          // NB x 4
#define OFF_CNT    (OFF_SUM + NB * 4)            // int completion counter
#define OFF_BEST   (OFF_CNT + 1)                 // NG global best-per-gt

// ---------- shared math helpers ----------

// IoU and areas must be bitwise identical between kA (scan) and kB (force
// re-scan): contraction pinned off; identical inlined op sequences.
static __device__ __forceinline__ float area_of(float4 b) {
#pragma clang fp contract(off)
    return (b.z - b.x) * (b.w - b.y);
}

static __device__ __forceinline__ float iou_one(
    float gx0, float gy0, float gx1, float gy1, float ga,
    float ax0, float ay0, float ax1, float ay1, float aa)
{
#pragma clang fp contract(off)
    float ltx = fmaxf(gx0, ax0);
    float lty = fmaxf(gy0, ay0);
    float rbx = fminf(gx1, ax1);
    float rby = fminf(gy1, ay1);
    float w = fmaxf(rbx - ltx, 0.0f);
    float h = fmaxf(rby - lty, 0.0f);
    float inter = w * h;
    float uni = ga + aa - inter;
    return inter * __builtin_amdgcn_rcpf(uni);   // uni > 0 always
}

static __device__ __forceinline__ float smooth_l1_f(float d) {
    const float BETA = 1.0f / 9.0f;
    float ad = fabsf(d);
    return (ad < BETA) ? (0.5f * d * d / BETA) : (ad - 0.5f * BETA);
}

// ---------- kernel A: unified anchor-major scan (+ROI blocks) ----------
// blocks [0,NB): per-anchor max/argmax -> maxarg; per-(g,block) max -> table.
// blocks [NB,NB+RBLK): ROI losses -> OFF_ROI; zero table pad columns.

__global__ __launch_bounds__(256) void kA(const float4* __restrict__ anchors,
                                          const float4* __restrict__ gt,
                                          const float* __restrict__ logits,
                                          const float* __restrict__ breg,
                                          const int* __restrict__ rlab,
                                          const float4* __restrict__ rtgt,
                                          const float* __restrict__ rsc,
                                          float* __restrict__ ws) {
    int t = threadIdx.x;
    int b = blockIdx.x;

    if (b >= NB) {
        // ---- ROI block ----
        int r = b - NB;
        // zero table pad columns for rows [4r, 4r+4)
        if (t < NBP - NB) {
#pragma unroll
            for (int row = 0; row < 4; row++)
                ws[OFF_TAB + (4 * r + row) * NBP + NB + t] = 0.0f;
        }
        __shared__ float rbuf[4][2];
        int p = r * 256 + t;                 // 16*256 == NP
        float l0 = logits[2 * p], l1 = logits[2 * p + 1];
        float mx = fmaxf(l0, l1);
        float lse = mx + __logf(__expf(l0 - mx) + __expf(l1 - mx));
        float s = rsc[p];
        float clsl = -((1.0f - s) * (l0 - lse) + s * (l1 - lse));

        int lbl = rlab[p];
        int cl = lbl < 0 ? 0 : lbl;
        float4 bb = *(const float4*)(breg + 8 * p + 4 * cl);
        float4 tg = rtgt[p];
        float sl = smooth_l1_f(bb.x - tg.x) + smooth_l1_f(bb.y - tg.y) +
                   smooth_l1_f(bb.z - tg.z) + smooth_l1_f(bb.w - tg.w);
        float boxl = (lbl > 0) ? sl : 0.0f;

        int lane = t & 63, w = t >> 6;
        for (int off = 32; off > 0; off >>= 1) {
            clsl += __shfl_down(clsl, off);
            boxl += __shfl_down(boxl, off);
        }
        if (lane == 0) { rbuf[w][0] = clsl; rbuf[w][1] = boxl; }
        __syncthreads();
        if (t == 0) {
            float s0 = 0.f, s1 = 0.f;
            for (int i = 0; i < 4; i++) { s0 += rbuf[i][0]; s1 += rbuf[i][1]; }
            ws[OFF_ROI + 2 * r] = s0;
            ws[OFF_ROI + 2 * r + 1] = s1;
        }
        return;
    }

    // ---- scan block ----
    int a0 = b * SPAN + t;
    int a1 = a0 + 256;
    bool ok0 = a0 < NA, ok1 = a1 < NA;
    float4 av0 = ok0 ? anchors[a0] : make_float4(0.f, 0.f, 0.f, 0.f);
    float4 av1 = ok1 ? anchors[a1] : make_float4(0.f, 0.f, 0.f, 0.f);
    float aa0 = area_of(av0);
    float aa1 = area_of(av1);

    float m[NG];
#pragma unroll
    for (int g = 0; g < NG; g++) m[g] = 0.0f;

    float max0 = -1.0f, max1 = -1.0f;
    int arg0 = 0, arg1 = 0;
#pragma unroll
    for (int g = 0; g < NG; g++) {
        float4 G = gt[g];                    // uniform -> s_load
        float ga = area_of(G);
        float u0 = iou_one(G.x, G.y, G.z, G.w, ga, av0.x, av0.y, av0.z, av0.w, aa0);
        float u1 = iou_one(G.x, G.y, G.z, G.w, ga, av1.x, av1.y, av1.z, av1.w, aa1);
        if (u0 > max0) { max0 = u0; arg0 = g; }   // first-max == jnp.argmax
        if (u1 > max1) { max1 = u1; arg1 = g; }
        m[g] = fmaxf(m[g], fmaxf(u0, u1));        // fake anchors give 0: harmless
    }

    float2* ma = (float2*)(ws + OFF_MAXARG);
    if (ok0) ma[a0] = make_float2(max0, __int_as_float(arg0));
    if (ok1) ma[a1] = make_float2(max1, __int_as_float(arg1));

    // per-(g,block) reduce: 6 shuffles per g, then 4-wave LDS combine
    __shared__ float sred[4][NG];
    int lane = t & 63, w = t >> 6;
#pragma unroll
    for (int g = 0; g < NG; g++) {
        float mm = m[g];
        for (int off = 32; off > 0; off >>= 1)
            mm = fmaxf(mm, __shfl_down(mm, off));
        if (lane == 0) sred[w][g] = mm;
    }
    __syncthreads();
    if (t < NG) {
        float mm = fmaxf(fmaxf(sred[0][t], sred[1][t]),
                         fmaxf(sred[2][t], sred[3][t]));
        ws[OFF_TAB + t * NBP + b] = mm;      // plain store
    }
}

// ---------- kernel F: tiny best-per-gt reduce (64 blocks) ----------
// block g: reduce table row g (512 floats) -> ws[OFF_BEST+g].
// No force re-scan here (kB does it in-register for its own anchors).
// block 0 re-inits the kB completion counter.

__global__ __launch_bounds__(256) void kFs(float* __restrict__ ws) {
    __shared__ float swm[4];
    int t = threadIdx.x;
    int g = blockIdx.x;
    if (g == 0 && t == 0) *(int*)(ws + OFF_CNT) = 0;
    const float* row = ws + OFF_TAB + g * NBP;
    float v = fmaxf(row[t], row[t + 256]);
    int lane = t & 63, w = t >> 6;
    for (int off = 32; off > 0; off >>= 1)
        v = fmaxf(v, __shfl_down(v, off));
    if (lane == 0) swm[w] = v;
    __syncthreads();
    if (t == 0)
        ws[OFF_BEST + g] = fmaxf(fmaxf(swm[0], swm[1]),
                                 fmaxf(swm[2], swm[3]));
}

// ---------- kernel B: in-register force + epilogue + last-block finish ----
// Each block: (1) read best[g] (64 floats, L2-hot); candidates = {g :
// tab[g][b] == best[g]} (usually 0-1 per block); (2) re-scan ONLY this
// block's anchors vs candidates (bitwise-identical iou) -> force in regs;
// (3) per-anchor labels + losses; (4) partial sums; last-arriving block
// performs the old kernel-C double-precision reduce and writes out.

__global__ __launch_bounds__(256) void kB(const float4* __restrict__ anchors,
                                          const float* __restrict__ objness,
                                          const float4* __restrict__ pdel,
                                          const float4* __restrict__ gt,
                                          const float* __restrict__ gscore,
                                          const int* __restrict__ gconf,
                                          float* __restrict__ ws,
                                          float* __restrict__ out) {
    __shared__ float sbest[NG];
    __shared__ int   scand[NG];
    __shared__ int   scnt;
    __shared__ float rbuf[4][4];
    __shared__ bool  islast;

    int t = threadIdx.x;
    int b = blockIdx.x;
    int lane = t & 63, w = t >> 6;

    if (t == 0) scnt = 0;
    __syncthreads();

    // ---- (1) candidate gts for this block ----
    if (t < NG) {
        float bv = ws[OFF_BEST + t];
        sbest[t] = bv;
        if (ws[OFF_TAB + t * NBP + b] == bv) {
            int i = atomicAdd(&scnt, 1);
            scand[i] = t;
        }
    }
    __syncthreads();
    int cnt = scnt;

    const float2* ma = (const float2*)(ws + OFF_MAXARG);

    float posf = 0.f, negf = 0.f, slpos = 0.f, bces = 0.f;
#pragma unroll
    for (int k = 0; k < 2; k++) {
        int a = b * SPAN + k * 256 + t;
        if (a >= NA) continue;
        float2 mv = ma[a];
        float maxv = mv.x;
        int arg = __float_as_int(mv.y);

        float4 av = anchors[a];
        float aa = area_of(av);

        // in-register force detection (replaces old force-byte pass)
        bool force = false;
        for (int i = 0; i < cnt; i++) {
            int g = scand[i];
            float4 G = gt[g];                // uniform -> s_load
            float ga = area_of(G);
            float u = iou_one(G.x, G.y, G.z, G.w, ga, av.x, av.y, av.z, av.w, aa);
            force |= (u == sbest[g]);
        }

        int matched = (maxv < 0.3f) ? -1 : ((maxv < 0.7f) ? -2 : arg);
        if (force) matched = arg;
        int cl = matched < 0 ? 0 : matched;

        float4 Ac = gt[cl];                  // per-lane gather, 1KB L1-hot
        float score = gscore[cl];
        int conf = gconf[cl];
        float label = (matched >= 0) ? 1.0f : 0.0f;
        label = fminf(label, score);
        if (matched == -1) label = 0.0f;
        if (matched == -2) label = -1.0f;
        if (conf == 0 && matched >= 0) label = -1.0f;

        bool pos = (label >= 1.0f);
        bool neg = (label == 0.0f);
        bool sel = pos || neg;

        float aw = av.z - av.x, ah = av.w - av.y;
        float acx = av.x + 0.5f * aw, acy = av.y + 0.5f * ah;
        float gw = Ac.z - Ac.x, gh = Ac.w - Ac.y;
        float gcx = Ac.x + 0.5f * gw, gcy = Ac.y + 0.5f * gh;
        float t0 = (gcx - acx) / aw;
        float t1 = (gcy - acy) / ah;
        float t2 = __logf(gw / aw);
        float t3 = __logf(gh / ah);

        float4 pd = pdel[a];
        float sl = smooth_l1_f(pd.x - t0) + smooth_l1_f(pd.y - t1) +
                   smooth_l1_f(pd.z - t2) + smooth_l1_f(pd.w - t3);

        float x = objness[a];
        float y = sel ? fminf(fmaxf(label, 0.0f), 1.0f) : 0.0f;
        float bce = fmaxf(x, 0.0f) - x * y + __logf(1.0f + __expf(-fabsf(x)));

        if (pos) { posf += 1.0f; slpos += sl; }
        if (neg) negf += 1.0f;
        if (sel) bces += bce;
    }

    for (int off = 32; off > 0; off >>= 1) {
        posf  += __shfl_down(posf, off);
        negf  += __shfl_down(negf, off);
        slpos += __shfl_down(slpos, off);
        bces  += __shfl_down(bces, off);
    }
    if (lane == 0) { rbuf[w][0] = posf; rbuf[w][1] = negf; rbuf[w][2] = slpos; rbuf[w][3] = bces; }
    __syncthreads();
    if (t == 0) {
        float s0 = 0.f, s1 = 0.f, s2 = 0.f, s3 = 0.f;
        for (int i = 0; i < 4; i++) { s0 += rbuf[i][0]; s1 += rbuf[i][1]; s2 += rbuf[i][2]; s3 += rbuf[i][3]; }
        float* r = ws + OFF_SUM + 4 * b;
        r[0] = s0; r[1] = s1; r[2] = s2; r[3] = s3;
        __threadfence();                                   // release partials
        int prev = atomicAdd((int*)(ws + OFF_CNT), 1);     // device-scope
        islast = (prev == NB - 1);
    }
    __syncthreads();
    if (!islast) return;
    __threadfence();                                       // acquire partials

    // ---- (4) final reduce (old kernel C), last block only ----
    __shared__ double sredc[4][6];
    double a0 = 0, a1 = 0, a2 = 0, a3 = 0, c0 = 0, c1 = 0;
    for (int r = t; r < NB; r += 256) {
        const float4 v = *(const float4*)(ws + OFF_SUM + 4 * r);
        a0 += v.x; a1 += v.y; a2 += v.z; a3 += v.w;
    }
    if (t < RBLK) {
        c0 = ws[OFF_ROI + 2 * t];
        c1 = ws[OFF_ROI + 2 * t + 1];
    }
    for (int off = 32; off > 0; off >>= 1) {
        a0 += __shfl_down(a0, off);
        a1 += __shfl_down(a1, off);
        a2 += __shfl_down(a2, off);
        a3 += __shfl_down(a3, off);
        c0 += __shfl_down(c0, off);
        c1 += __shfl_down(c1, off);
    }
    if (lane == 0) {
        sredc[w][0] = a0; sredc[w][1] = a1; sredc[w][2] = a2;
        sredc[w][3] = a3; sredc[w][4] = c0; sredc[w][5] = c1;
    }
    __syncthreads();
    if (t == 0) {
        double s[6] = {0, 0, 0, 0, 0, 0};
        for (int i = 0; i < 4; i++)
            for (int j = 0; j < 6; j++) s[j] += sredc[i][j];
        double n = s[0] + s[1];
        out[0] = (float)(s[3] / n);            // objectness_loss
        out[1] = (float)(s[2] / n);            // rpn_box_loss
        out[2] = (float)(s[4] / (double)NP);   // classification_loss
        out[3] = (float)(s[5] / (double)NP);   // roi_box_loss
    }
}

extern "C" void kernel_launch(void* const* d_in, const int* in_sizes, int n_in,
                              void* d_out, int out_size, void* d_ws, size_t ws_size,
                              hipStream_t stream) {
    const float4* anchors = (const float4*)d_in[0];
    const float4* gt      = (const float4*)d_in[1];
    const float*  gscore  = (const float*)d_in[2];
    const int*    gconf   = (const int*)d_in[3];
    const float*  objness = (const float*)d_in[4];
    const float4* pdel    = (const float4*)d_in[5];
    const float*  clog    = (const float*)d_in[6];
    const float*  breg    = (const float*)d_in[7];
    const int*    rlab    = (const int*)d_in[8];
    const float4* rtgt    = (const float4*)d_in[9];
    const float*  rsc     = (const float*)d_in[10];

    float* ws = (float*)d_ws;
    float* out = (float*)d_out;

    kA<<<NB + RBLK, 256, 0, stream>>>(anchors, gt, clog, breg, rlab, rtgt, rsc, ws);
    kFs<<<NG, 256, 0, stream>>>(ws);
    kB<<<NB, 256, 0, stream>>>(anchors, objness, pdel, gt, gscore, gconf, ws, out);
}

// Round 3
// 113.028 us; speedup vs baseline: 1.0880x; 1.0375x over previous
//
#include <hip/hip_runtime.h>
#include <math.h>

#define NA 250000
#define NG 64
#define NP 4096

#define SPAN 512                        // anchors per scan block
#define NB ((NA + SPAN - 1) / SPAN)     // 489 scan blocks
#define NBP 512                         // padded best-table width
#define RBLK (NP / 256)                 // 16 ROI blocks (appended to kA)

// ws float layout
#define OFF_TAB    0                             // [NG][NBP] per-(g,block) max
#define OFF_MAXARG (OFF_TAB + NG * NBP)          // float2 per anchor: (max, arg bits)
#define OFF_ROI    (OFF_MAXARG + 2 * NB * SPAN)  // 16 x 2
#define OFF_SUM    (OFF_ROI + RBLK * 2)          // NB x 4 (no-force partials)

#define CAND_MAX 256
#define FMAX 512

// ---------- shared math helpers ----------

// IoU and areas must be bitwise identical between kA (scan) and kFC (force
// re-scan): contraction pinned off; identical inlined op sequences.
static __device__ __forceinline__ float area_of(float4 b) {
#pragma clang fp contract(off)
    return (b.z - b.x) * (b.w - b.y);
}

static __device__ __forceinline__ float iou_one(
    float gx0, float gy0, float gx1, float gy1, float ga,
    float ax0, float ay0, float ax1, float ay1, float aa)
{
#pragma clang fp contract(off)
    float ltx = fmaxf(gx0, ax0);
    float lty = fmaxf(gy0, ay0);
    float rbx = fminf(gx1, ax1);
    float rby = fminf(gy1, ay1);
    float w = fmaxf(rbx - ltx, 0.0f);
    float h = fmaxf(rby - lty, 0.0f);
    float inter = w * h;
    float uni = ga + aa - inter;
    return inter * __builtin_amdgcn_rcpf(uni);   // uni > 0 always
}

static __device__ __forceinline__ float smooth_l1_f(float d) {
    const float BETA = 1.0f / 9.0f;
    float ad = fabsf(d);
    return (ad < BETA) ? (0.5f * d * d / BETA) : (ad - 0.5f * BETA);
}

// per-anchor RPN contribution with NO force applied (force fixed up later
// as a double-precision delta in kFC — force only affects maxv<0.7 anchors)
static __device__ __forceinline__ void contrib_noforce(
    float4 av, float maxv, int arg, float4 pd, float x,
    const float4* __restrict__ gt, const float* __restrict__ gscore,
    const int* __restrict__ gconf,
    float& posf, float& negf, float& slpos, float& bces)
{
    int matched = (maxv < 0.3f) ? -1 : ((maxv < 0.7f) ? -2 : arg);
    int cl = matched < 0 ? 0 : matched;

    float4 Ac = gt[cl];                  // per-lane gather, 1KB L1-hot
    float score = gscore[cl];
    int conf = gconf[cl];
    float label = (matched >= 0) ? 1.0f : 0.0f;
    label = fminf(label, score);
    if (matched == -1) label = 0.0f;
    if (matched == -2) label = -1.0f;
    if (conf == 0 && matched >= 0) label = -1.0f;

    bool pos = (label >= 1.0f);
    bool neg = (label == 0.0f);
    bool sel = pos || neg;

    float aw = av.z - av.x, ah = av.w - av.y;
    float acx = av.x + 0.5f * aw, acy = av.y + 0.5f * ah;
    float gw = Ac.z - Ac.x, gh = Ac.w - Ac.y;
    float gcx = Ac.x + 0.5f * gw, gcy = Ac.y + 0.5f * gh;
    float t0 = (gcx - acx) / aw;
    float t1 = (gcy - acy) / ah;
    float t2 = __logf(gw / aw);
    float t3 = __logf(gh / ah);

    float sl = smooth_l1_f(pd.x - t0) + smooth_l1_f(pd.y - t1) +
               smooth_l1_f(pd.z - t2) + smooth_l1_f(pd.w - t3);

    float y = sel ? fminf(fmaxf(label, 0.0f), 1.0f) : 0.0f;
    float bce = fmaxf(x, 0.0f) - x * y + __logf(1.0f + __expf(-fabsf(x)));

    if (pos) { posf += 1.0f; slpos += sl; }
    if (neg) negf += 1.0f;
    if (sel) bces += bce;
}

// ---------- kernel A: scan + fused no-force epilogue (+ROI blocks) -------
// blocks [0,NB): per-anchor max/argmax (kept in regs AND written to maxarg
//   for kFC); per-(g,block) max -> table via 63-shuffle transpose reduce;
//   fused per-anchor losses (no force) -> SUM partials.
// blocks [NB,NB+RBLK): ROI losses -> OFF_ROI; zero table pad columns.

__global__ __launch_bounds__(256) void kA(const float4* __restrict__ anchors,
                                          const float4* __restrict__ gt,
                                          const float* __restrict__ logits,
                                          const float* __restrict__ breg,
                                          const int* __restrict__ rlab,
                                          const float4* __restrict__ rtgt,
                                          const float* __restrict__ rsc,
                                          const float* __restrict__ objness,
                                          const float4* __restrict__ pdel,
                                          const float* __restrict__ gscore,
                                          const int* __restrict__ gconf,
                                          float* __restrict__ ws) {
    int t = threadIdx.x;
    int b = blockIdx.x;

    if (b >= NB) {
        // ---- ROI block ----
        int r = b - NB;
        // zero table pad columns for rows [4r, 4r+4)
        if (t < NBP - NB) {
#pragma unroll
            for (int row = 0; row < 4; row++)
                ws[OFF_TAB + (4 * r + row) * NBP + NB + t] = 0.0f;
        }
        __shared__ float rbuf2[4][2];
        int p = r * 256 + t;                 // 16*256 == NP
        float l0 = logits[2 * p], l1 = logits[2 * p + 1];
        float mx = fmaxf(l0, l1);
        float lse = mx + __logf(__expf(l0 - mx) + __expf(l1 - mx));
        float s = rsc[p];
        float clsl = -((1.0f - s) * (l0 - lse) + s * (l1 - lse));

        int lbl = rlab[p];
        int cl = lbl < 0 ? 0 : lbl;
        float4 bb = *(const float4*)(breg + 8 * p + 4 * cl);
        float4 tg = rtgt[p];
        float sl = smooth_l1_f(bb.x - tg.x) + smooth_l1_f(bb.y - tg.y) +
                   smooth_l1_f(bb.z - tg.z) + smooth_l1_f(bb.w - tg.w);
        float boxl = (lbl > 0) ? sl : 0.0f;

        int lane = t & 63, w = t >> 6;
        for (int off = 32; off > 0; off >>= 1) {
            clsl += __shfl_down(clsl, off);
            boxl += __shfl_down(boxl, off);
        }
        if (lane == 0) { rbuf2[w][0] = clsl; rbuf2[w][1] = boxl; }
        __syncthreads();
        if (t == 0) {
            float s0 = 0.f, s1 = 0.f;
            for (int i = 0; i < 4; i++) { s0 += rbuf2[i][0]; s1 += rbuf2[i][1]; }
            ws[OFF_ROI + 2 * r] = s0;
            ws[OFF_ROI + 2 * r + 1] = s1;
        }
        return;
    }

    // ---- scan block ----
    int a0 = b * SPAN + t;
    int a1 = a0 + 256;
    bool ok0 = a0 < NA, ok1 = a1 < NA;
    float4 av0 = ok0 ? anchors[a0] : make_float4(0.f, 0.f, 0.f, 0.f);
    float4 av1 = ok1 ? anchors[a1] : make_float4(0.f, 0.f, 0.f, 0.f);
    float aa0 = area_of(av0);
    float aa1 = area_of(av1);

    float m[NG];
    float max0 = -1.0f, max1 = -1.0f;
    int arg0 = 0, arg1 = 0;
#pragma unroll
    for (int g = 0; g < NG; g++) {
        float4 G = gt[g];                    // uniform -> s_load
        float ga = area_of(G);
        float u0 = iou_one(G.x, G.y, G.z, G.w, ga, av0.x, av0.y, av0.z, av0.w, aa0);
        float u1 = iou_one(G.x, G.y, G.z, G.w, ga, av1.x, av1.y, av1.z, av1.w, aa1);
        if (u0 > max0) { max0 = u0; arg0 = g; }   // first-max == jnp.argmax
        if (u1 > max1) { max1 = u1; arg1 = g; }
        m[g] = fmaxf(u0, u1);                     // fake anchors give 0: harmless
    }

    float2* ma = (float2*)(ws + OFF_MAXARG);
    if (ok0) ma[a0] = make_float2(max0, __int_as_float(arg0));
    if (ok1) ma[a1] = make_float2(max1, __int_as_float(arg1));

    int lane = t & 63, w = t >> 6;

    // per-(g,wave) max via bit-reverse transpose reduce: 63 shuffles total
    // (vs 64*6=384).  After stage s, each lane holds 32>>s values covering
    // a chunk selected by bit s of lane; final m[0] = wave max of
    // g = bitrev6(lane).  fmax is exact -> table bitwise identical.
#pragma unroll
    for (int s = 0; s < 6; s++) {
        int half = 32 >> s;
        bool up = (lane >> s) & 1;
#pragma unroll
        for (int j = 0; j < half; j++) {
            float mine = up ? m[j] : m[j + half];
            float keep = up ? m[j + half] : m[j];
            float oth  = __shfl_xor(mine, 1 << s);
            m[j] = fmaxf(keep, oth);
        }
    }
    int grev = ((lane & 1) << 5) | ((lane & 2) << 3) | ((lane & 4) << 1) |
               ((lane & 8) >> 1) | ((lane & 16) >> 3) | ((lane & 32) >> 5);
    __shared__ float sred[4][NG];
    sred[w][grev] = m[0];
    __syncthreads();
    if (t < NG) {
        float mm = fmaxf(fmaxf(sred[0][t], sred[1][t]),
                         fmaxf(sred[2][t], sred[3][t]));
        ws[OFF_TAB + t * NBP + b] = mm;      // plain store
    }

    // ---- fused epilogue (no force; anchors/max/arg still in registers) ----
    float posf = 0.f, negf = 0.f, slpos = 0.f, bces = 0.f;
    if (ok0) {
        float4 pd = pdel[a0];
        float x = objness[a0];
        contrib_noforce(av0, max0, arg0, pd, x, gt, gscore, gconf,
                        posf, negf, slpos, bces);
    }
    if (ok1) {
        float4 pd = pdel[a1];
        float x = objness[a1];
        contrib_noforce(av1, max1, arg1, pd, x, gt, gscore, gconf,
                        posf, negf, slpos, bces);
    }

    for (int off = 32; off > 0; off >>= 1) {
        posf  += __shfl_down(posf, off);
        negf  += __shfl_down(negf, off);
        slpos += __shfl_down(slpos, off);
        bces  += __shfl_down(bces, off);
    }
    __shared__ float rbuf[4][4];
    if (lane == 0) { rbuf[w][0] = posf; rbuf[w][1] = negf; rbuf[w][2] = slpos; rbuf[w][3] = bces; }
    __syncthreads();
    if (t == 0) {
        float s0 = 0.f, s1 = 0.f, s2 = 0.f, s3 = 0.f;
        for (int i = 0; i < 4; i++) { s0 += rbuf[i][0]; s1 += rbuf[i][1]; s2 += rbuf[i][2]; s3 += rbuf[i][3]; }
        float* r = ws + OFF_SUM + 4 * b;
        r[0] = s0; r[1] = s1; r[2] = s2; r[3] = s3;   // plain stores
    }
}

// ---------- kernel FC: best-per-gt + force deltas + final reduce ----------
// ONE block, 1024 threads, no fences (all kA writes visible via dispatch
// boundary).  Phases:
//  1: row-reduce table -> best[g] (LDS); candidate (g,span) list where
//     tab[g][s] == best[g].
//  2: rescan candidate spans; anchor forced iff iou(g,a) == best[g]
//     (bitwise-identical iou).  Only maxv<0.7 anchors change under force
//     (maxv>=0.7 already matched=arg) -> collect those.
//  3: dedup (force = ANY g); per unique forced anchor compute contribution
//     delta (forced minus no-force) in f32.
//  4: final reduce = exact old-kC order over SUM/ROI partials (t<256),
//     then t0 adds deltas serially in double and writes out.

__global__ __launch_bounds__(1024) void kFC(const float4* __restrict__ anchors,
                                            const float4* __restrict__ gt,
                                            const float* __restrict__ objness,
                                            const float4* __restrict__ pdel,
                                            const float* __restrict__ gscore,
                                            const int* __restrict__ gconf,
                                            float* __restrict__ ws,
                                            float* __restrict__ out) {
    __shared__ float sbest[NG];
    __shared__ int   cand[CAND_MAX];
    __shared__ int   ccnt, fcnt;
    __shared__ int   flist[FMAX];
    __shared__ float sdn[FMAX], sdb[FMAX], sds[FMAX];
    __shared__ double sredc[4][6];

    int t = threadIdx.x;
    int lane = t & 63, w = t >> 6;
    if (t == 0) { ccnt = 0; fcnt = 0; }
    __syncthreads();

    // ---- phase 1: 16 waves x 4 rows each ----
#pragma unroll
    for (int i = 0; i < 4; i++) {
        int g = w * 4 + i;
        const float* row = ws + OFF_TAB + g * NBP;
        float v[8];
        float mm = 0.0f;
#pragma unroll
        for (int p = 0; p < 8; p++) v[p] = row[lane + 64 * p];
#pragma unroll
        for (int p = 0; p < 8; p++) mm = fmaxf(mm, v[p]);
#pragma unroll
        for (int off = 1; off < 64; off <<= 1)
            mm = fmaxf(mm, __shfl_xor(mm, off));       // butterfly: all lanes get max
        if (lane == 0) sbest[g] = mm;
#pragma unroll
        for (int p = 0; p < 8; p++) {
            if (v[p] == mm) {
                int idx = atomicAdd(&ccnt, 1);
                if (idx < CAND_MAX) cand[idx] = (g << 16) | (lane + 64 * p);
            }
        }
    }
    __syncthreads();

    // ---- phase 2: rescan candidate spans (filtered) ----
    const float2* ma = (const float2*)(ws + OFF_MAXARG);
    int nc = min(ccnt, CAND_MAX);
    int tot = nc << 9;                       // nc * 512 anchors
    for (int idx = t; idx < tot; idx += 1024) {
        int e = idx >> 9, i = idx & 511;
        int gs = cand[e];
        int g = gs >> 16, s = gs & 0xffff;
        int a = s * SPAN + i;
        if (a >= NA) continue;
        float bestg = sbest[g];
        float2 mv = ma[a];
        // iou(g,a) <= maxv, so maxv < bestg can't achieve it; maxv >= 0.7
        // anchors have matched==arg with or without force -> delta 0.
        if (mv.x < bestg || mv.x >= 0.7f) continue;
        float4 G = gt[g];
        float4 av = anchors[a];
        float u = iou_one(G.x, G.y, G.z, G.w, area_of(G),
                          av.x, av.y, av.z, av.w, area_of(av));
        if (u == bestg) {
            int fi = atomicAdd(&fcnt, 1);
            if (fi < FMAX) flist[fi] = a;
        }
    }
    __syncthreads();

    // ---- phase 3: dedup + per-anchor force delta ----
    int fc = min(fcnt, FMAX);
    for (int i = t; i < fc; i += 1024) {
        int a = flist[i];
        bool dup = false;
        for (int j = 0; j < i; j++) dup = dup || (flist[j] == a);
        float dN = 0.f, dB = 0.f, dS = 0.f;
        if (!dup) {
            float2 mv = ma[a];
            float maxv = mv.x;
            int arg = __float_as_int(mv.y);
            float x = objness[a];
            float bceY0 = fmaxf(x, 0.0f) + __logf(1.0f + __expf(-fabsf(x)));  // y=0
            // old (no force), maxv<0.7 guaranteed:
            float n0 = 0.f, b0 = 0.f;
            if (maxv < 0.3f) { n0 = 1.0f; b0 = bceY0; }      // label=0 -> neg
            // (maxv in [0.3,0.7): label=-1 -> contributes nothing)
            // new (forced): matched = arg
            float sc = gscore[arg];
            int cf = gconf[arg];
            float label1 = fminf(1.0f, sc);
            if (cf == 0) label1 = -1.0f;
            bool pos1 = (label1 >= 1.0f);
            bool neg1 = (label1 == 0.0f);
            bool sel1 = pos1 || neg1;
            float n1 = (pos1 ? 1.f : 0.f) + (neg1 ? 1.f : 0.f);
            float y1 = sel1 ? fminf(fmaxf(label1, 0.0f), 1.0f) : 0.0f;
            float b1 = sel1 ? (fmaxf(x, 0.0f) - x * y1 +
                               __logf(1.0f + __expf(-fabsf(x)))) : 0.0f;
            float s1v = 0.f;
            if (pos1) {                      // gscore>=1: ~never, but exact path
                float4 av = anchors[a];
                float4 Ac = gt[arg];
                float4 pd = pdel[a];
                float aw = av.z - av.x, ah = av.w - av.y;
                float acx = av.x + 0.5f * aw, acy = av.y + 0.5f * ah;
                float gw = Ac.z - Ac.x, gh = Ac.w - Ac.y;
                float gcx = Ac.x + 0.5f * gw, gcy = Ac.y + 0.5f * gh;
                float t0v = (gcx - acx) / aw, t1v = (gcy - acy) / ah;
                float t2v = __logf(gw / aw), t3v = __logf(gh / ah);
                s1v = smooth_l1_f(pd.x - t0v) + smooth_l1_f(pd.y - t1v) +
                      smooth_l1_f(pd.z - t2v) + smooth_l1_f(pd.w - t3v);
            }
            dN = n1 - n0;
            dB = b1 - b0;
            dS = s1v;
        }
        sdn[i] = dN; sdb[i] = dB; sds[i] = dS;
    }
    __syncthreads();

    // ---- phase 4: final reduce, exact old-kC structure among t<256 ----
    double a0 = 0, a1 = 0, a2 = 0, a3 = 0, c0 = 0, c1 = 0;
    if (t < 256) {
        for (int r = t; r < NB; r += 256) {
            const float4 v = *(const float4*)(ws + OFF_SUM + 4 * r);
            a0 += v.x; a1 += v.y; a2 += v.z; a3 += v.w;
        }
        if (t < RBLK) {
            c0 = ws[OFF_ROI + 2 * t];
            c1 = ws[OFF_ROI + 2 * t + 1];
        }
        for (int off = 32; off > 0; off >>= 1) {
            a0 += __shfl_down(a0, off);
            a1 += __shfl_down(a1, off);
            a2 += __shfl_down(a2, off);
            a3 += __shfl_down(a3, off);
            c0 += __shfl_down(c0, off);
            c1 += __shfl_down(c1, off);
        }
        if (lane == 0) {
            sredc[w][0] = a0; sredc[w][1] = a1; sredc[w][2] = a2;
            sredc[w][3] = a3; sredc[w][4] = c0; sredc[w][5] = c1;
        }
    }
    __syncthreads();
    if (t == 0) {
        double s[6] = {0, 0, 0, 0, 0, 0};
        for (int i = 0; i < 4; i++)
            for (int j = 0; j < 6; j++) s[j] += sredc[i][j];
        double Dn = 0, Db = 0, Ds = 0;
        for (int i = 0; i < fc; i++) { Dn += sdn[i]; Db += sdb[i]; Ds += sds[i]; }
        double n = s[0] + s[1] + Dn;
        out[0] = (float)((s[3] + Db) / n);     // objectness_loss
        out[1] = (float)((s[2] + Ds) / n);     // rpn_box_loss
        out[2] = (float)(s[4] / (double)NP);   // classification_loss
        out[3] = (float)(s[5] / (double)NP);   // roi_box_loss
    }
}

extern "C" void kernel_launch(void* const* d_in, const int* in_sizes, int n_in,
                              void* d_out, int out_size, void* d_ws, size_t ws_size,
                              hipStream_t stream) {
    const float4* anchors = (const float4*)d_in[0];
    const float4* gt      = (const float4*)d_in[1];
    const float*  gscore  = (const float*)d_in[2];
    const int*    gconf   = (const int*)d_in[3];
    const float*  objness = (const float*)d_in[4];
    const float4* pdel    = (const float4*)d_in[5];
    const float*  clog    = (const float*)d_in[6];
    const float*  breg    = (const float*)d_in[7];
    const int*    rlab    = (const int*)d_in[8];
    const float4* rtgt    = (const float4*)d_in[9];
    const float*  rsc     = (const float*)d_in[10];

    float* ws = (float*)d_ws;
    float* out = (float*)d_out;

    kA<<<NB + RBLK, 256, 0, stream>>>(anchors, gt, clog, breg, rlab, rtgt, rsc,
                                      objness, pdel, gscore, gconf, ws);
    kFC<<<1, 1024, 0, stream>>>(anchors, gt, objness, pdel, gscore, gconf, ws, out);
}

// Round 4
// 110.392 us; speedup vs baseline: 1.1140x; 1.0239x over previous
//
#include <hip/hip_runtime.h>
#include <math.h>

#define NA 250000
#define NG 64
#define NP 4096

#define SPAN 512                        // anchors per scan block
#define NB ((NA + SPAN - 1) / SPAN)     // 489 scan blocks
#define NBP 512                         // padded best-table width
#define RBLK (NP / 256)                 // 16 ROI blocks (appended to kA)

// ws float layout
#define OFF_TAB    0                             // [NG][NBP] per-(g,block) max
#define OFF_MAXARG (OFF_TAB + NG * NBP)          // float2 per anchor: (max, arg bits)
#define OFF_ROI    (OFF_MAXARG + 2 * NB * SPAN)  // 16 x 2
#define OFF_SUM    (OFF_ROI + RBLK * 2)          // NB x 4 (no-force partials)

#define CAND_MAX 256
#define FMAX 512

// ---------- shared math helpers ----------

// IoU and areas must be bitwise identical between kA (scan) and kFC (force
// re-scan): contraction pinned off; identical inlined op sequences.
static __device__ __forceinline__ float area_of(float4 b) {
#pragma clang fp contract(off)
    return (b.z - b.x) * (b.w - b.y);
}

static __device__ __forceinline__ float iou_one(
    float gx0, float gy0, float gx1, float gy1, float ga,
    float ax0, float ay0, float ax1, float ay1, float aa)
{
#pragma clang fp contract(off)
    float ltx = fmaxf(gx0, ax0);
    float lty = fmaxf(gy0, ay0);
    float rbx = fminf(gx1, ax1);
    float rby = fminf(gy1, ay1);
    float w = fmaxf(rbx - ltx, 0.0f);
    float h = fmaxf(rby - lty, 0.0f);
    float inter = w * h;
    float uni = ga + aa - inter;
    return inter * __builtin_amdgcn_rcpf(uni);   // uni > 0 always
}

static __device__ __forceinline__ float smooth_l1_f(float d) {
    const float BETA = 1.0f / 9.0f;
    float ad = fabsf(d);
    return (ad < BETA) ? (0.5f * d * d / BETA) : (ad - 0.5f * BETA);
}

// per-anchor RPN contribution with NO force applied (force fixed up later
// as a double-precision delta in kFC — force only affects maxv<0.7 anchors).
// Encode/smooth-l1/pdel-load are LAZY under pos (pos needs gscore>=1.0,
// rare/never): semantics-preserving for all inputs, skips 2 transcendentals,
// the gt[cl] gather, and the whole pdel stream when no lane is pos.
static __device__ __forceinline__ void contrib_noforce(
    float4 av, float maxv, int arg, const float4* __restrict__ pdel, int a,
    float x,
    const float4* __restrict__ gt, const float* __restrict__ gscore,
    const int* __restrict__ gconf,
    float& posf, float& negf, float& slpos, float& bces)
{
    int matched = (maxv < 0.3f) ? -1 : ((maxv < 0.7f) ? -2 : arg);
    int cl = matched < 0 ? 0 : matched;

    float score = gscore[cl];
    int conf = gconf[cl];
    float label = (matched >= 0) ? 1.0f : 0.0f;
    label = fminf(label, score);
    if (matched == -1) label = 0.0f;
    if (matched == -2) label = -1.0f;
    if (conf == 0 && matched >= 0) label = -1.0f;

    bool pos = (label >= 1.0f);
    bool neg = (label == 0.0f);
    bool sel = pos || neg;

    if (pos) {
        float4 Ac = gt[cl];              // per-lane gather, 1KB L1-hot
        float4 pd = pdel[a];
        float aw = av.z - av.x, ah = av.w - av.y;
        float acx = av.x + 0.5f * aw, acy = av.y + 0.5f * ah;
        float gw = Ac.z - Ac.x, gh = Ac.w - Ac.y;
        float gcx = Ac.x + 0.5f * gw, gcy = Ac.y + 0.5f * gh;
        float t0 = (gcx - acx) / aw;
        float t1 = (gcy - acy) / ah;
        float t2 = __logf(gw / aw);
        float t3 = __logf(gh / ah);
        float sl = smooth_l1_f(pd.x - t0) + smooth_l1_f(pd.y - t1) +
                   smooth_l1_f(pd.z - t2) + smooth_l1_f(pd.w - t3);
        posf += 1.0f;
        slpos += sl;
    }

    float y = sel ? fminf(fmaxf(label, 0.0f), 1.0f) : 0.0f;
    float bce = fmaxf(x, 0.0f) - x * y + __logf(1.0f + __expf(-fabsf(x)));

    if (neg) negf += 1.0f;
    if (sel) bces += bce;
}

// ---------- kernel A: scan + fused no-force epilogue (+ROI blocks) -------
// blocks [0,NB): per-anchor max/argmax (kept in regs AND written to maxarg
//   for kFC); per-(g,block) max -> table via 63-shuffle transpose reduce;
//   fused per-anchor losses (no force) -> SUM partials.
// blocks [NB,NB+RBLK): ROI losses -> OFF_ROI; zero table pad columns.

__global__ __launch_bounds__(256) void kA(const float4* __restrict__ anchors,
                                          const float4* __restrict__ gt,
                                          const float* __restrict__ logits,
                                          const float* __restrict__ breg,
                                          const int* __restrict__ rlab,
                                          const float4* __restrict__ rtgt,
                                          const float* __restrict__ rsc,
                                          const float* __restrict__ objness,
                                          const float4* __restrict__ pdel,
                                          const float* __restrict__ gscore,
                                          const int* __restrict__ gconf,
                                          float* __restrict__ ws) {
    int t = threadIdx.x;
    int b = blockIdx.x;

    if (b >= NB) {
        // ---- ROI block ----
        int r = b - NB;
        // zero table pad columns for rows [4r, 4r+4)
        if (t < NBP - NB) {
#pragma unroll
            for (int row = 0; row < 4; row++)
                ws[OFF_TAB + (4 * r + row) * NBP + NB + t] = 0.0f;
        }
        __shared__ float rbuf2[4][2];
        int p = r * 256 + t;                 // 16*256 == NP
        float l0 = logits[2 * p], l1 = logits[2 * p + 1];
        float mx = fmaxf(l0, l1);
        float lse = mx + __logf(__expf(l0 - mx) + __expf(l1 - mx));
        float s = rsc[p];
        float clsl = -((1.0f - s) * (l0 - lse) + s * (l1 - lse));

        int lbl = rlab[p];
        int cl = lbl < 0 ? 0 : lbl;
        float4 bb = *(const float4*)(breg + 8 * p + 4 * cl);
        float4 tg = rtgt[p];
        float sl = smooth_l1_f(bb.x - tg.x) + smooth_l1_f(bb.y - tg.y) +
                   smooth_l1_f(bb.z - tg.z) + smooth_l1_f(bb.w - tg.w);
        float boxl = (lbl > 0) ? sl : 0.0f;

        int lane = t & 63, w = t >> 6;
        for (int off = 32; off > 0; off >>= 1) {
            clsl += __shfl_down(clsl, off);
            boxl += __shfl_down(boxl, off);
        }
        if (lane == 0) { rbuf2[w][0] = clsl; rbuf2[w][1] = boxl; }
        __syncthreads();
        if (t == 0) {
            float s0 = 0.f, s1 = 0.f;
            for (int i = 0; i < 4; i++) { s0 += rbuf2[i][0]; s1 += rbuf2[i][1]; }
            ws[OFF_ROI + 2 * r] = s0;
            ws[OFF_ROI + 2 * r + 1] = s1;
        }
        return;
    }

    // ---- scan block ----
    int a0 = b * SPAN + t;
    int a1 = a0 + 256;
    bool ok0 = a0 < NA, ok1 = a1 < NA;
    float4 av0 = ok0 ? anchors[a0] : make_float4(0.f, 0.f, 0.f, 0.f);
    float4 av1 = ok1 ? anchors[a1] : make_float4(0.f, 0.f, 0.f, 0.f);
    float aa0 = area_of(av0);
    float aa1 = area_of(av1);

    float m[NG];
    float max0 = -1.0f, max1 = -1.0f;
    int arg0 = 0, arg1 = 0;
#pragma unroll
    for (int g = 0; g < NG; g++) {
        float4 G = gt[g];                    // uniform -> s_load
        float ga = area_of(G);
        float u0 = iou_one(G.x, G.y, G.z, G.w, ga, av0.x, av0.y, av0.z, av0.w, aa0);
        float u1 = iou_one(G.x, G.y, G.z, G.w, ga, av1.x, av1.y, av1.z, av1.w, aa1);
        if (u0 > max0) { max0 = u0; arg0 = g; }   // first-max == jnp.argmax
        if (u1 > max1) { max1 = u1; arg1 = g; }
        m[g] = fmaxf(u0, u1);                     // fake anchors give 0: harmless
    }

    float2* ma = (float2*)(ws + OFF_MAXARG);
    if (ok0) ma[a0] = make_float2(max0, __int_as_float(arg0));
    if (ok1) ma[a1] = make_float2(max1, __int_as_float(arg1));

    int lane = t & 63, w = t >> 6;

    // per-(g,wave) max via bit-reverse transpose reduce: 63 shuffles total
    // (vs 64*6=384).  After stage s, each lane holds 32>>s values covering
    // a chunk selected by bit s of lane; final m[0] = wave max of
    // g = bitrev6(lane).  fmax is exact -> table bitwise identical.
#pragma unroll
    for (int s = 0; s < 6; s++) {
        int half = 32 >> s;
        bool up = (lane >> s) & 1;
#pragma unroll
        for (int j = 0; j < half; j++) {
            float mine = up ? m[j] : m[j + half];
            float keep = up ? m[j + half] : m[j];
            float oth  = __shfl_xor(mine, 1 << s);
            m[j] = fmaxf(keep, oth);
        }
    }
    int grev = ((lane & 1) << 5) | ((lane & 2) << 3) | ((lane & 4) << 1) |
               ((lane & 8) >> 1) | ((lane & 16) >> 3) | ((lane & 32) >> 5);
    __shared__ float sred[4][NG];
    sred[w][grev] = m[0];
    __syncthreads();
    if (t < NG) {
        float mm = fmaxf(fmaxf(sred[0][t], sred[1][t]),
                         fmaxf(sred[2][t], sred[3][t]));
        ws[OFF_TAB + t * NBP + b] = mm;      // plain store
    }

    // ---- fused epilogue (no force; anchors/max/arg still in registers) ----
    float posf = 0.f, negf = 0.f, slpos = 0.f, bces = 0.f;
    if (ok0) {
        float x = objness[a0];
        contrib_noforce(av0, max0, arg0, pdel, a0, x, gt, gscore, gconf,
                        posf, negf, slpos, bces);
    }
    if (ok1) {
        float x = objness[a1];
        contrib_noforce(av1, max1, arg1, pdel, a1, x, gt, gscore, gconf,
                        posf, negf, slpos, bces);
    }

    for (int off = 32; off > 0; off >>= 1) {
        posf  += __shfl_down(posf, off);
        negf  += __shfl_down(negf, off);
        slpos += __shfl_down(slpos, off);
        bces  += __shfl_down(bces, off);
    }
    __shared__ float rbuf[4][4];
    if (lane == 0) { rbuf[w][0] = posf; rbuf[w][1] = negf; rbuf[w][2] = slpos; rbuf[w][3] = bces; }
    __syncthreads();
    if (t == 0) {
        float s0 = 0.f, s1 = 0.f, s2 = 0.f, s3 = 0.f;
        for (int i = 0; i < 4; i++) { s0 += rbuf[i][0]; s1 += rbuf[i][1]; s2 += rbuf[i][2]; s3 += rbuf[i][3]; }
        float* r = ws + OFF_SUM + 4 * b;
        r[0] = s0; r[1] = s1; r[2] = s2; r[3] = s3;   // plain stores
    }
}

// ---------- kernel FC: best-per-gt + force deltas + final reduce ----------
// ONE block, 1024 threads, no fences (all kA writes visible via dispatch
// boundary).  Phases:
//  1: row-reduce table (float4 loads) -> best[g] (LDS); candidate (g,span)
//     list where tab[g][s] == best[g].
//  2: rescan candidate spans; anchor forced iff iou(g,a) == best[g]
//     (bitwise-identical iou).  Only maxv<0.7 anchors change under force
//     (maxv>=0.7 already matched=arg) -> collect those.
//  3: dedup (force = ANY g); per unique forced anchor compute contribution
//     delta (forced minus no-force) in f32.
//  4: final reduce = exact old-kC order over SUM/ROI partials (t<256),
//     then t0 adds deltas serially in double and writes out.

__global__ __launch_bounds__(1024) void kFC(const float4* __restrict__ anchors,
                                            const float4* __restrict__ gt,
                                            const float* __restrict__ objness,
                                            const float4* __restrict__ pdel,
                                            const float* __restrict__ gscore,
                                            const int* __restrict__ gconf,
                                            float* __restrict__ ws,
                                            float* __restrict__ out) {
    __shared__ float sbest[NG];
    __shared__ int   cand[CAND_MAX];
    __shared__ int   ccnt, fcnt;
    __shared__ int   flist[FMAX];
    __shared__ float sdn[FMAX], sdb[FMAX], sds[FMAX];
    __shared__ double sredc[4][6];

    int t = threadIdx.x;
    int lane = t & 63, w = t >> 6;
    if (t == 0) { ccnt = 0; fcnt = 0; }
    __syncthreads();

    // ---- phase 1: 16 waves x 4 rows each, float4 table reads ----
#pragma unroll
    for (int i = 0; i < 4; i++) {
        int g = w * 4 + i;
        const float4* rowv = (const float4*)(ws + OFF_TAB + g * NBP);
        float4 v0 = rowv[lane];            // cols 4*lane   .. 4*lane+3
        float4 v1 = rowv[lane + 64];       // cols 256+4*lane .. +3
        float mm = fmaxf(fmaxf(fmaxf(v0.x, v0.y), fmaxf(v0.z, v0.w)),
                         fmaxf(fmaxf(v1.x, v1.y), fmaxf(v1.z, v1.w)));
#pragma unroll
        for (int off = 1; off < 64; off <<= 1)
            mm = fmaxf(mm, __shfl_xor(mm, off));   // butterfly: all lanes get max
        if (lane == 0) sbest[g] = mm;
        int c0 = 4 * lane, c1 = 4 * (lane + 64);
        if (v0.x == mm) { int idx = atomicAdd(&ccnt, 1); if (idx < CAND_MAX) cand[idx] = (g << 16) | (c0 + 0); }
        if (v0.y == mm) { int idx = atomicAdd(&ccnt, 1); if (idx < CAND_MAX) cand[idx] = (g << 16) | (c0 + 1); }
        if (v0.z == mm) { int idx = atomicAdd(&ccnt, 1); if (idx < CAND_MAX) cand[idx] = (g << 16) | (c0 + 2); }
        if (v0.w == mm) { int idx = atomicAdd(&ccnt, 1); if (idx < CAND_MAX) cand[idx] = (g << 16) | (c0 + 3); }
        if (v1.x == mm) { int idx = atomicAdd(&ccnt, 1); if (idx < CAND_MAX) cand[idx] = (g << 16) | (c1 + 0); }
        if (v1.y == mm) { int idx = atomicAdd(&ccnt, 1); if (idx < CAND_MAX) cand[idx] = (g << 16) | (c1 + 1); }
        if (v1.z == mm) { int idx = atomicAdd(&ccnt, 1); if (idx < CAND_MAX) cand[idx] = (g << 16) | (c1 + 2); }
        if (v1.w == mm) { int idx = atomicAdd(&ccnt, 1); if (idx < CAND_MAX) cand[idx] = (g << 16) | (c1 + 3); }
    }
    __syncthreads();

    // ---- phase 2: rescan candidate spans (filtered) ----
    const float2* ma = (const float2*)(ws + OFF_MAXARG);
    int nc = min(ccnt, CAND_MAX);
    int tot = nc << 9;                       // nc * 512 anchors
    for (int idx = t; idx < tot; idx += 1024) {
        int e = idx >> 9, i = idx & 511;
        int gs = cand[e];
        int g = gs >> 16, s = gs & 0xffff;
        int a = s * SPAN + i;
        if (a >= NA) continue;
        float bestg = sbest[g];
        float2 mv = ma[a];
        // iou(g,a) <= maxv, so maxv < bestg can't achieve it; maxv >= 0.7
        // anchors have matched==arg with or without force -> delta 0.
        if (mv.x < bestg || mv.x >= 0.7f) continue;
        float4 G = gt[g];
        float4 av = anchors[a];
        float u = iou_one(G.x, G.y, G.z, G.w, area_of(G),
                          av.x, av.y, av.z, av.w, area_of(av));
        if (u == bestg) {
            int fi = atomicAdd(&fcnt, 1);
            if (fi < FMAX) flist[fi] = a;
        }
    }
    __syncthreads();

    // ---- phase 3: dedup + per-anchor force delta ----
    int fc = min(fcnt, FMAX);
    for (int i = t; i < fc; i += 1024) {
        int a = flist[i];
        bool dup = false;
        for (int j = 0; j < i; j++) dup = dup || (flist[j] == a);
        float dN = 0.f, dB = 0.f, dS = 0.f;
        if (!dup) {
            float2 mv = ma[a];
            float maxv = mv.x;
            int arg = __float_as_int(mv.y);
            float x = objness[a];
            float bceY0 = fmaxf(x, 0.0f) + __logf(1.0f + __expf(-fabsf(x)));  // y=0
            // old (no force), maxv<0.7 guaranteed:
            float n0 = 0.f, b0 = 0.f;
            if (maxv < 0.3f) { n0 = 1.0f; b0 = bceY0; }      // label=0 -> neg
            // (maxv in [0.3,0.7): label=-1 -> contributes nothing)
            // new (forced): matched = arg
            float sc = gscore[arg];
            int cf = gconf[arg];
            float label1 = fminf(1.0f, sc);
            if (cf == 0) label1 = -1.0f;
            bool pos1 = (label1 >= 1.0f);
            bool neg1 = (label1 == 0.0f);
            bool sel1 = pos1 || neg1;
            float n1 = (pos1 ? 1.f : 0.f) + (neg1 ? 1.f : 0.f);
            float y1 = sel1 ? fminf(fmaxf(label1, 0.0f), 1.0f) : 0.0f;
            float b1 = sel1 ? (fmaxf(x, 0.0f) - x * y1 +
                               __logf(1.0f + __expf(-fabsf(x)))) : 0.0f;
            float s1v = 0.f;
            if (pos1) {                      // gscore>=1: ~never, but exact path
                float4 av = anchors[a];
                float4 Ac = gt[arg];
                float4 pd = pdel[a];
                float aw = av.z - av.x, ah = av.w - av.y;
                float acx = av.x + 0.5f * aw, acy = av.y + 0.5f * ah;
                float gw = Ac.z - Ac.x, gh = Ac.w - Ac.y;
                float gcx = Ac.x + 0.5f * gw, gcy = Ac.y + 0.5f * gh;
                float t0v = (gcx - acx) / aw, t1v = (gcy - acy) / ah;
                float t2v = __logf(gw / aw), t3v = __logf(gh / ah);
                s1v = smooth_l1_f(pd.x - t0v) + smooth_l1_f(pd.y - t1v) +
                      smooth_l1_f(pd.z - t2v) + smooth_l1_f(pd.w - t3v);
            }
            dN = n1 - n0;
            dB = b1 - b0;
            dS = s1v;
        }
        sdn[i] = dN; sdb[i] = dB; sds[i] = dS;
    }
    __syncthreads();

    // ---- phase 4: final reduce, exact old-kC structure among t<256 ----
    double a0 = 0, a1 = 0, a2 = 0, a3 = 0, c0 = 0, c1 = 0;
    if (t < 256) {
        for (int r = t; r < NB; r += 256) {
            const float4 v = *(const float4*)(ws + OFF_SUM + 4 * r);
            a0 += v.x; a1 += v.y; a2 += v.z; a3 += v.w;
        }
        if (t < RBLK) {
            c0 = ws[OFF_ROI + 2 * t];
            c1 = ws[OFF_ROI + 2 * t + 1];
        }
        for (int off = 32; off > 0; off >>= 1) {
            a0 += __shfl_down(a0, off);
            a1 += __shfl_down(a1, off);
            a2 += __shfl_down(a2, off);
            a3 += __shfl_down(a3, off);
            c0 += __shfl_down(c0, off);
            c1 += __shfl_down(c1, off);
        }
        if (lane == 0) {
            sredc[w][0] = a0; sredc[w][1] = a1; sredc[w][2] = a2;
            sredc[w][3] = a3; sredc[w][4] = c0; sredc[w][5] = c1;
        }
    }
    __syncthreads();
    if (t == 0) {
        double s[6] = {0, 0, 0, 0, 0, 0};
        for (int i = 0; i < 4; i++)
            for (int j = 0; j < 6; j++) s[j] += sredc[i][j];
        double Dn = 0, Db = 0, Ds = 0;
        for (int i = 0; i < fc; i++) { Dn += sdn[i]; Db += sdb[i]; Ds += sds[i]; }
        double n = s[0] + s[1] + Dn;
        out[0] = (float)((s[3] + Db) / n);     // objectness_loss
        out[1] = (float)((s[2] + Ds) / n);     // rpn_box_loss
        out[2] = (float)(s[4] / (double)NP);   // classification_loss
        out[3] = (float)(s[5] / (double)NP);   // roi_box_loss
    }
}

extern "C" void kernel_launch(void* const* d_in, const int* in_sizes, int n_in,
                              void* d_out, int out_size, void* d_ws, size_t ws_size,
                              hipStream_t stream) {
    const float4* anchors = (const float4*)d_in[0];
    const float4* gt      = (const float4*)d_in[1];
    const float*  gscore  = (const float*)d_in[2];
    const int*    gconf   = (const int*)d_in[3];
    const float*  objness = (const float*)d_in[4];
    const float4* pdel    = (const float4*)d_in[5];
    const float*  clog    = (const float*)d_in[6];
    const float*  breg    = (const float*)d_in[7];
    const int*    rlab    = (const int*)d_in[8];
    const float4* rtgt    = (const float4*)d_in[9];
    const float*  rsc     = (const float*)d_in[10];

    float* ws = (float*)d_ws;
    float* out = (float*)d_out;

    kA<<<NB + RBLK, 256, 0, stream>>>(anchors, gt, clog, breg, rlab, rtgt, rsc,
                                      objness, pdel, gscore, gconf, ws);
    kFC<<<1, 1024, 0, stream>>>(anchors, gt, objness, pdel, gscore, gconf, ws, out);
}